// Round 3
// baseline (161.809 us; speedup 1.0000x reference)
//
#include <hip/hip_runtime.h>
#include <math.h>

#define BB_ 4096      // batch
#define DD_ 64        // emb dim
#define NI_ 10000     // items
#define SW 193        // padded LDS stride for transposed weights (193%32=1 -> conflict-free)

// ---------------- threefry2x32 (JAX PRNG, key=42, partitionable path) ----------------
// jax_threefry_partitionable=True (modern default):
//   counter = uint64 index i, split (hi, lo) = (i>>32, i&0xffffffff) = (0, i) for i<2^32
//   (bits1, bits2) = threefry2x32(key=(0,42), (hi, lo))
//   32-bit bits = bits1 ^ bits2
//   uniform = float(bits>>9 | 0x3F800000) - 1
__device__ inline unsigned rotl32(unsigned x, unsigned r){ return (x<<r)|(x>>(32u-r)); }

__device__ inline float jax_uniform_key42(int i){
  const unsigned k0 = 0u, k1 = 42u;                 // jax.random.key(42) -> (0, 42)
  const unsigned ks2 = 0x1BD11BDAu ^ k0 ^ k1;
  unsigned x0 = 0u, x1 = (unsigned)i;               // counter (hi, lo) = (0, i)
  unsigned ks[3] = {k0, k1, ks2};
  x0 += ks[0]; x1 += ks[1];
  const unsigned R0[4] = {13u,15u,26u,6u};
  const unsigned R1[4] = {17u,29u,16u,24u};
  #pragma unroll
  for (int it = 0; it < 5; ++it){
    const unsigned* R = (it & 1) ? R1 : R0;
    #pragma unroll
    for (int j = 0; j < 4; ++j){ x0 += x1; x1 = rotl32(x1, R[j]); x1 ^= x0; }
    x0 += ks[(it+1)%3];
    x1 += ks[(it+2)%3] + (unsigned)(it+1);
  }
  unsigned bits = x0 ^ x1;                          // partitionable 32-bit tail: XOR both words
  unsigned f = (bits >> 9) | 0x3F800000u;           // [1,2)
  return __uint_as_float(f) - 1.0f;                 // [0,1)
}

// ---------------- kernel 1: histogram + weighted matvec over cov + combined ----------------
__global__ __launch_bounds__(256) void matvec_combined_kernel(
    const int* __restrict__ v, const float* __restrict__ returns,
    const float* __restrict__ cov, float* __restrict__ combined)
{
  __shared__ __align__(16) float w[NI_];
  __shared__ float red[4];
  const int tid = threadIdx.x;
  for (int i = tid; i < NI_; i += 256) w[i] = 0.0f;
  __syncthreads();
  for (int i = tid; i < BB_; i += 256) atomicAdd(&w[v[i]], 1.0f);
  __syncthreads();

  const int lane = tid & 63, wid = tid >> 6;
  const float4* w4 = (const float4*)w;

  for (int row = blockIdx.x; row < NI_; row += gridDim.x) {
    const float4* r4 = (const float4*)(cov + (size_t)row * NI_);
    float acc = 0.0f;
    for (int k = tid; k < NI_/4; k += 256) {
      float4 c = r4[k];
      float4 ww = w4[k];
      acc += c.x*ww.x + c.y*ww.y + c.z*ww.z + c.w*ww.w;
    }
    #pragma unroll
    for (int off = 32; off > 0; off >>= 1) acc += __shfl_down(acc, off);
    if (lane == 0) red[wid] = acc;
    __syncthreads();
    if (tid == 0) {
      float s = red[0] + red[1] + red[2] + red[3];
      float cov_val = s * (1.0f / (float)BB_);
      float mv = returns[row] - 0.5f * cov_val;       // GAMMA = 1
      float pref = jax_uniform_key42(row);
      combined[row] = 0.5f * mv + 0.5f * pref;        // LAM = 0.5
    }
    __syncthreads();
  }
}

// ---------------- kernel 2: global top-5 + per-row pos/neg selection ----------------
__device__ inline unsigned long long shfl_down_u64(unsigned long long x, int off){
  unsigned lo = (unsigned)(x & 0xFFFFFFFFull), hi = (unsigned)(x >> 32);
  lo = __shfl_down(lo, off); hi = __shfl_down(hi, off);
  return ((unsigned long long)hi << 32) | (unsigned long long)lo;
}

__global__ __launch_bounds__(1024) void top5_items_kernel(
    const float* __restrict__ combined, const int* __restrict__ v,
    float* __restrict__ pos_out, float* __restrict__ neg_out)
{
  __shared__ unsigned long long redL[16];
  __shared__ int chosen[5];
  const int tid = threadIdx.x, lane = tid & 63, wid = tid >> 6;

  for (int r = 0; r < 5; ++r) {
    unsigned long long best = 0ull;
    for (int i = tid; i < NI_; i += 1024) {
      bool skip = false;
      for (int c = 0; c < r; ++c) if (chosen[c] == i) skip = true;
      if (skip) continue;
      unsigned u = __float_as_uint(combined[i]);
      u ^= (u >> 31) ? 0xFFFFFFFFu : 0x80000000u;      // order-preserving float->uint
      unsigned long long key = ((unsigned long long)u << 32)
                             | (unsigned long long)(0xFFFFFFFFu - (unsigned)i); // tie: lower idx wins
      if (key > best) best = key;
    }
    #pragma unroll
    for (int off = 32; off > 0; off >>= 1) {
      unsigned long long o = shfl_down_u64(best, off);
      if (o > best) best = o;
    }
    if (lane == 0) redL[wid] = best;
    __syncthreads();
    if (tid == 0) {
      unsigned long long b = redL[0];
      for (int wv = 1; wv < 16; ++wv) if (redL[wv] > b) b = redL[wv];
      chosen[r] = (int)(0xFFFFFFFFu - (unsigned)(b & 0xFFFFFFFFull));
    }
    __syncthreads();
  }

  for (int b = tid; b < BB_; b += 1024) {
    int vb = v[b];
    int f[4]; int n = 0;
    #pragma unroll
    for (int c = 0; c < 5; ++c) { if (n < 4 && chosen[c] != vb) f[n++] = chosen[c]; }
    pos_out[b]       = (float)f[0];
    neg_out[b*3 + 0] = (float)f[1];
    neg_out[b*3 + 1] = (float)f[2];
    neg_out[b*3 + 2] = (float)f[3];
  }
}

// ---------------- kernel 3: GRU memory update -> h_new ----------------
__global__ __launch_bounds__(256) void gru_kernel(
    const int* __restrict__ u, const int* __restrict__ v,
    const float* __restrict__ delta_t, const float* __restrict__ edge_feat,
    const float* __restrict__ user_emb, const float* __restrict__ item_emb,
    const float* __restrict__ mem,
    const float* __restrict__ w_ih, const float* __restrict__ w_hh,
    const float* __restrict__ b_ih, const float* __restrict__ b_hh,
    float* __restrict__ h_new_out)
{
  __shared__ float WihT[130*SW];   // [j][k], k<192
  __shared__ float WhhT[64*SW];    // [j][k], k<192
  __shared__ float bih[192], bhh[192];
  const int tid = threadIdx.x;

  for (int idx = tid; idx < 192*130; idx += 256) {
    int k = idx / 130, j = idx - k*130;
    WihT[j*SW + k] = w_ih[idx];
  }
  for (int idx = tid; idx < 192*64; idx += 256) {
    int k = idx >> 6, j = idx & 63;
    WhhT[j*SW + k] = w_hh[idx];
  }
  if (tid < 192) { bih[tid] = b_ih[tid]; bhh[tid] = b_hh[tid]; }
  __syncthreads();

  const int lane = tid & 63, wid = tid >> 6;
  const int rowbase = blockIdx.x * 16 + wid * 4;

  float u_d[4], v_d[4], h_d[4], dt[4], ef[4];
  int bb[4];
  #pragma unroll
  for (int rr = 0; rr < 4; ++rr) {
    int b = rowbase + rr; bb[rr] = b;
    int uu = u[b], vv = v[b];
    u_d[rr] = user_emb[uu*64 + lane];
    v_d[rr] = item_emb[vv*64 + lane];
    h_d[rr] = mem[uu*64 + lane];
    dt[rr]  = delta_t[b];
    ef[rr]  = edge_feat[b];
  }

  float biR = bih[lane], biZ = bih[64+lane], biN = bih[128+lane];
  float bhR = bhh[lane], bhZ = bhh[64+lane], bhN = bhh[128+lane];
  float accR[4], accZ[4], accN[4], hN[4];
  #pragma unroll
  for (int rr = 0; rr < 4; ++rr) { accR[rr]=biR+bhR; accZ[rr]=biZ+bhZ; accN[rr]=biN; hN[rr]=bhN; }

  // msg[0:64] = u_emb
  for (int j = 0; j < 64; ++j) {
    float wR = WihT[j*SW + lane], wZ = WihT[j*SW + 64 + lane], wN = WihT[j*SW + 128 + lane];
    #pragma unroll
    for (int rr = 0; rr < 4; ++rr) {
      float m = __shfl(u_d[rr], j);
      accR[rr] = fmaf(wR, m, accR[rr]); accZ[rr] = fmaf(wZ, m, accZ[rr]); accN[rr] = fmaf(wN, m, accN[rr]);
    }
  }
  // msg[64:128] = v_emb
  for (int j = 0; j < 64; ++j) {
    float wR = WihT[(64+j)*SW + lane], wZ = WihT[(64+j)*SW + 64 + lane], wN = WihT[(64+j)*SW + 128 + lane];
    #pragma unroll
    for (int rr = 0; rr < 4; ++rr) {
      float m = __shfl(v_d[rr], j);
      accR[rr] = fmaf(wR, m, accR[rr]); accZ[rr] = fmaf(wZ, m, accZ[rr]); accN[rr] = fmaf(wN, m, accN[rr]);
    }
  }
  // msg[128] = delta_t, msg[129] = edge_feat
  {
    float wR = WihT[128*SW + lane], wZ = WihT[128*SW + 64 + lane], wN = WihT[128*SW + 128 + lane];
    #pragma unroll
    for (int rr = 0; rr < 4; ++rr) {
      accR[rr] = fmaf(wR, dt[rr], accR[rr]); accZ[rr] = fmaf(wZ, dt[rr], accZ[rr]); accN[rr] = fmaf(wN, dt[rr], accN[rr]);
    }
    float eR = WihT[129*SW + lane], eZ = WihT[129*SW + 64 + lane], eN = WihT[129*SW + 128 + lane];
    #pragma unroll
    for (int rr = 0; rr < 4; ++rr) {
      accR[rr] = fmaf(eR, ef[rr], accR[rr]); accZ[rr] = fmaf(eZ, ef[rr], accZ[rr]); accN[rr] = fmaf(eN, ef[rr], accN[rr]);
    }
  }
  // gh: h @ W_hh^T  (r,z fold into acc; n kept separate)
  for (int j = 0; j < 64; ++j) {
    float wR = WhhT[j*SW + lane], wZ = WhhT[j*SW + 64 + lane], wN = WhhT[j*SW + 128 + lane];
    #pragma unroll
    for (int rr = 0; rr < 4; ++rr) {
      float m = __shfl(h_d[rr], j);
      accR[rr] = fmaf(wR, m, accR[rr]); accZ[rr] = fmaf(wZ, m, accZ[rr]); hN[rr] = fmaf(wN, m, hN[rr]);
    }
  }

  #pragma unroll
  for (int rr = 0; rr < 4; ++rr) {
    float r = 1.0f / (1.0f + expf(-accR[rr]));
    float z = 1.0f / (1.0f + expf(-accZ[rr]));
    float n = tanhf(accN[rr] + r * hN[rr]);
    float hn = (1.0f - z) * n + z * h_d[rr];
    h_new_out[bb[rr]*64 + lane] = hn;
  }
}

// ---------------- kernel 4: 2-token 4-head attention + out-proj -> z_u ----------------
__global__ __launch_bounds__(256) void attn_kernel(
    const int* __restrict__ u, const int* __restrict__ v,
    const float* __restrict__ edge_feat,
    const float* __restrict__ user_emb, const float* __restrict__ item_emb,
    const float* __restrict__ in_w, const float* __restrict__ in_b,
    const float* __restrict__ out_w, const float* __restrict__ out_b,
    float* __restrict__ z_out)
{
  __shared__ float inT[64*SW];     // [j][k], j<64, k<192
  __shared__ float outT[64*65];    // [j][k], j,k<64
  __shared__ float binp[192];
  __shared__ float bout[64];
  const int tid = threadIdx.x;

  for (int idx = tid; idx < 192*64; idx += 256) {
    int k = idx >> 6, j = idx & 63;
    inT[j*SW + k] = in_w[idx];
  }
  for (int idx = tid; idx < 64*64; idx += 256) {
    int k = idx >> 6, j = idx & 63;
    outT[j*65 + k] = out_w[idx];
  }
  if (tid < 192) binp[tid] = in_b[tid];
  if (tid < 64)  bout[tid] = out_b[tid];
  __syncthreads();

  const int lane = tid & 63, wid = tid >> 6;
  const int rowbase = blockIdx.x * 8 + wid * 2;

  float u_d[2], x1_d[2];
  int bb[2];
  #pragma unroll
  for (int rr = 0; rr < 2; ++rr) {
    int b = rowbase + rr; bb[rr] = b;
    int uu = u[b], vv = v[b];
    float ef = edge_feat[b];
    u_d[rr]  = user_emb[uu*64 + lane];
    x1_d[rr] = item_emb[vv*64 + lane] + ef;
  }

  float bq = binp[lane], bk = binp[64+lane], bv = binp[128+lane];
  float q0[2], k0[2], v0[2], k1[2], v1[2];
  #pragma unroll
  for (int rr = 0; rr < 2; ++rr) { q0[rr]=bq; k0[rr]=bk; v0[rr]=bv; k1[rr]=bk; v1[rr]=bv; }

  for (int j = 0; j < 64; ++j) {
    float wq = inT[j*SW + lane], wk = inT[j*SW + 64 + lane], wv = inT[j*SW + 128 + lane];
    #pragma unroll
    for (int rr = 0; rr < 2; ++rr) {
      float x0 = __shfl(u_d[rr], j);
      float x1 = __shfl(x1_d[rr], j);
      q0[rr] = fmaf(wq, x0, q0[rr]);
      k0[rr] = fmaf(wk, x0, k0[rr]);
      v0[rr] = fmaf(wv, x0, v0[rr]);
      k1[rr] = fmaf(wk, x1, k1[rr]);
      v1[rr] = fmaf(wv, x1, v1[rr]);
    }
  }

  #pragma unroll
  for (int rr = 0; rr < 2; ++rr) {
    // per-head (16-lane group) dot products
    float p0 = q0[rr]*k0[rr], p1 = q0[rr]*k1[rr];
    #pragma unroll
    for (int off = 1; off < 16; off <<= 1) { p0 += __shfl_xor(p0, off); p1 += __shfl_xor(p1, off); }
    float s0 = p0 * 0.25f, s1 = p1 * 0.25f;
    float m  = fmaxf(s0, s1);
    float e0 = expf(s0 - m), e1 = expf(s1 - m);
    float inv = 1.0f / (e0 + e1);
    float o_d = (e0 * v0[rr] + e1 * v1[rr]) * inv;
    // out projection: z[lane] = b + sum_j o[j] * W_out[lane][j]
    float zacc = bout[lane];
    for (int j = 0; j < 64; ++j)
      zacc = fmaf(outT[j*65 + lane], __shfl(o_d, j), zacc);
    z_out[bb[rr]*64 + lane] = zacc;
  }
}

// ---------------- launch ----------------
extern "C" void kernel_launch(void* const* d_in, const int* in_sizes, int n_in,
                              void* d_out, int out_size, void* d_ws, size_t ws_size,
                              hipStream_t stream)
{
  const int*   u        = (const int*)d_in[0];
  const int*   v        = (const int*)d_in[1];
  /* t = d_in[2] unused */
  const float* delta_t  = (const float*)d_in[3];
  const float* edge_f   = (const float*)d_in[4];
  const float* returns  = (const float*)d_in[5];
  const float* cov      = (const float*)d_in[6];
  const float* user_emb = (const float*)d_in[7];
  const float* item_emb = (const float*)d_in[8];
  const float* mem      = (const float*)d_in[9];
  const float* w_ih     = (const float*)d_in[10];
  const float* w_hh     = (const float*)d_in[11];
  const float* b_ih     = (const float*)d_in[12];
  const float* b_hh     = (const float*)d_in[13];
  const float* in_w     = (const float*)d_in[14];
  const float* in_b     = (const float*)d_in[15];
  const float* out_w    = (const float*)d_in[16];
  const float* out_b    = (const float*)d_in[17];

  float* out     = (float*)d_out;
  float* z_out   = out;                    // B*D
  float* h_out   = out + BB_*DD_;          // B*D
  float* pos_out = out + 2*BB_*DD_;        // B
  float* neg_out = out + 2*BB_*DD_ + BB_;  // B*3

  float* combined = (float*)d_ws;          // NI_ floats

  hipLaunchKernelGGL(matvec_combined_kernel, dim3(1024), dim3(256), 0, stream,
                     v, returns, cov, combined);
  hipLaunchKernelGGL(top5_items_kernel, dim3(1), dim3(1024), 0, stream,
                     combined, v, pos_out, neg_out);
  hipLaunchKernelGGL(gru_kernel, dim3(256), dim3(256), 0, stream,
                     u, v, delta_t, edge_f, user_emb, item_emb, mem,
                     w_ih, w_hh, b_ih, b_hh, h_out);
  hipLaunchKernelGGL(attn_kernel, dim3(512), dim3(256), 0, stream,
                     u, v, edge_f, user_emb, item_emb,
                     in_w, in_b, out_w, out_b, z_out);
}

// Round 4
// 157.780 us; speedup vs baseline: 1.0255x; 1.0255x over previous
//
#include <hip/hip_runtime.h>
#include <math.h>

#define BB_ 4096      // batch
#define DD_ 64        // emb dim
#define NI_ 10000     // items
#define SW 193        // padded LDS stride for transposed weights (193%32=1 -> conflict-free)

// ---------------- threefry2x32 (JAX PRNG, key=42, partitionable path) ----------------
// bits[i] = xor(threefry2x32(key=(0,42), (0, i)));  uniform = float(bits>>9|0x3F800000)-1
__device__ inline unsigned rotl32(unsigned x, unsigned r){ return (x<<r)|(x>>(32u-r)); }

__device__ inline float jax_uniform_key42(int i){
  const unsigned k0 = 0u, k1 = 42u;
  const unsigned ks2 = 0x1BD11BDAu ^ k0 ^ k1;
  unsigned x0 = 0u, x1 = (unsigned)i;               // counter (hi, lo) = (0, i)
  unsigned ks[3] = {k0, k1, ks2};
  x0 += ks[0]; x1 += ks[1];
  const unsigned R0[4] = {13u,15u,26u,6u};
  const unsigned R1[4] = {17u,29u,16u,24u};
  #pragma unroll
  for (int it = 0; it < 5; ++it){
    const unsigned* R = (it & 1) ? R1 : R0;
    #pragma unroll
    for (int j = 0; j < 4; ++j){ x0 += x1; x1 = rotl32(x1, R[j]); x1 ^= x0; }
    x0 += ks[(it+1)%3];
    x1 += ks[(it+2)%3] + (unsigned)(it+1);
  }
  unsigned bits = x0 ^ x1;                          // partitionable 32-bit tail
  unsigned f = (bits >> 9) | 0x3F800000u;
  return __uint_as_float(f) - 1.0f;
}

// ---------------- kernel 1: histogram + wave-per-row weighted matvec ----------------
// 2500 blocks x 256 threads; wave w of block b owns row b*4+w. No barriers in the
// row loop -> full latency hiding; 40KB LDS histogram -> 4 blocks/CU.
__global__ __launch_bounds__(256) void matvec_combined_kernel(
    const int* __restrict__ v, const float* __restrict__ returns,
    const float* __restrict__ cov, float* __restrict__ combined)
{
  __shared__ __align__(16) float w[NI_];
  const int tid = threadIdx.x;
  for (int i = tid; i < NI_; i += 256) w[i] = 0.0f;
  __syncthreads();
  for (int i = tid; i < BB_; i += 256) atomicAdd(&w[v[i]], 1.0f);
  __syncthreads();

  const int lane = tid & 63, wid = tid >> 6;
  const int row = blockIdx.x * 4 + wid;             // gridDim = 2500 -> rows 0..9999
  const float4* w4 = (const float4*)w;
  const float4* r4 = (const float4*)(cov + (size_t)row * NI_);

  float acc0 = 0.0f, acc1 = 0.0f;
  // NI_/4 = 2500 float4 elements, strided by 128 (two 64-lane streams)
  int k = lane;
  for (; k + 64 < NI_/4; k += 128) {
    float4 c0 = r4[k],     ww0 = w4[k];
    float4 c1 = r4[k+64],  ww1 = w4[k+64];
    acc0 += c0.x*ww0.x + c0.y*ww0.y + c0.z*ww0.z + c0.w*ww0.w;
    acc1 += c1.x*ww1.x + c1.y*ww1.y + c1.z*ww1.z + c1.w*ww1.w;
  }
  if (k < NI_/4) {
    float4 c0 = r4[k], ww0 = w4[k];
    acc0 += c0.x*ww0.x + c0.y*ww0.y + c0.z*ww0.z + c0.w*ww0.w;
  }
  float acc = acc0 + acc1;
  #pragma unroll
  for (int off = 32; off > 0; off >>= 1) acc += __shfl_xor(acc, off);

  if (lane == 0) {
    float cov_val = acc * (1.0f / (float)BB_);
    float mv = returns[row] - 0.5f * cov_val;       // GAMMA = 1
    float pref = jax_uniform_key42(row);
    combined[row] = 0.5f * mv + 0.5f * pref;        // LAM = 0.5
  }
}

// ---------------- kernel 2: global top-5 + per-row pos/neg selection ----------------
__device__ inline unsigned long long shfl_down_u64(unsigned long long x, int off){
  unsigned lo = (unsigned)(x & 0xFFFFFFFFull), hi = (unsigned)(x >> 32);
  lo = __shfl_down(lo, off); hi = __shfl_down(hi, off);
  return ((unsigned long long)hi << 32) | (unsigned long long)lo;
}

__global__ __launch_bounds__(1024) void top5_items_kernel(
    const float* __restrict__ combined, const int* __restrict__ v,
    float* __restrict__ pos_out, float* __restrict__ neg_out)
{
  __shared__ unsigned long long redL[16];
  __shared__ int chosen[5];
  const int tid = threadIdx.x, lane = tid & 63, wid = tid >> 6;

  for (int r = 0; r < 5; ++r) {
    unsigned long long best = 0ull;
    for (int i = tid; i < NI_; i += 1024) {
      bool skip = false;
      for (int c = 0; c < r; ++c) if (chosen[c] == i) skip = true;
      if (skip) continue;
      unsigned u = __float_as_uint(combined[i]);
      u ^= (u >> 31) ? 0xFFFFFFFFu : 0x80000000u;      // order-preserving float->uint
      unsigned long long key = ((unsigned long long)u << 32)
                             | (unsigned long long)(0xFFFFFFFFu - (unsigned)i); // tie: lower idx wins
      if (key > best) best = key;
    }
    #pragma unroll
    for (int off = 32; off > 0; off >>= 1) {
      unsigned long long o = shfl_down_u64(best, off);
      if (o > best) best = o;
    }
    if (lane == 0) redL[wid] = best;
    __syncthreads();
    if (tid == 0) {
      unsigned long long b = redL[0];
      for (int wv = 1; wv < 16; ++wv) if (redL[wv] > b) b = redL[wv];
      chosen[r] = (int)(0xFFFFFFFFu - (unsigned)(b & 0xFFFFFFFFull));
    }
    __syncthreads();
  }

  for (int b = tid; b < BB_; b += 1024) {
    int vb = v[b];
    int f[4]; int n = 0;
    #pragma unroll
    for (int c = 0; c < 5; ++c) { if (n < 4 && chosen[c] != vb) f[n++] = chosen[c]; }
    pos_out[b]       = (float)f[0];
    neg_out[b*3 + 0] = (float)f[1];
    neg_out[b*3 + 1] = (float)f[2];
    neg_out[b*3 + 2] = (float)f[3];
  }
}

// ---------------- kernel 3: GRU memory update -> h_new ----------------
__global__ __launch_bounds__(256) void gru_kernel(
    const int* __restrict__ u, const int* __restrict__ v,
    const float* __restrict__ delta_t, const float* __restrict__ edge_feat,
    const float* __restrict__ user_emb, const float* __restrict__ item_emb,
    const float* __restrict__ mem,
    const float* __restrict__ w_ih, const float* __restrict__ w_hh,
    const float* __restrict__ b_ih, const float* __restrict__ b_hh,
    float* __restrict__ h_new_out)
{
  __shared__ float WihT[130*SW];   // [j][k], k<192
  __shared__ float WhhT[64*SW];    // [j][k], k<192
  __shared__ float bih[192], bhh[192];
  const int tid = threadIdx.x;

  for (int idx = tid; idx < 192*130; idx += 256) {
    int k = idx / 130, j = idx - k*130;
    WihT[j*SW + k] = w_ih[idx];
  }
  for (int idx = tid; idx < 192*64; idx += 256) {
    int k = idx >> 6, j = idx & 63;
    WhhT[j*SW + k] = w_hh[idx];
  }
  if (tid < 192) { bih[tid] = b_ih[tid]; bhh[tid] = b_hh[tid]; }
  __syncthreads();

  const int lane = tid & 63, wid = tid >> 6;
  const int rowbase = blockIdx.x * 16 + wid * 4;

  float u_d[4], v_d[4], h_d[4], dt[4], ef[4];
  int bb[4];
  #pragma unroll
  for (int rr = 0; rr < 4; ++rr) {
    int b = rowbase + rr; bb[rr] = b;
    int uu = u[b], vv = v[b];
    u_d[rr] = user_emb[uu*64 + lane];
    v_d[rr] = item_emb[vv*64 + lane];
    h_d[rr] = mem[uu*64 + lane];
    dt[rr]  = delta_t[b];
    ef[rr]  = edge_feat[b];
  }

  float biR = bih[lane], biZ = bih[64+lane], biN = bih[128+lane];
  float bhR = bhh[lane], bhZ = bhh[64+lane], bhN = bhh[128+lane];
  float accR[4], accZ[4], accN[4], hN[4];
  #pragma unroll
  for (int rr = 0; rr < 4; ++rr) { accR[rr]=biR+bhR; accZ[rr]=biZ+bhZ; accN[rr]=biN; hN[rr]=bhN; }

  // msg[0:64] = u_emb
  for (int j = 0; j < 64; ++j) {
    float wR = WihT[j*SW + lane], wZ = WihT[j*SW + 64 + lane], wN = WihT[j*SW + 128 + lane];
    #pragma unroll
    for (int rr = 0; rr < 4; ++rr) {
      float m = __shfl(u_d[rr], j);
      accR[rr] = fmaf(wR, m, accR[rr]); accZ[rr] = fmaf(wZ, m, accZ[rr]); accN[rr] = fmaf(wN, m, accN[rr]);
    }
  }
  // msg[64:128] = v_emb
  for (int j = 0; j < 64; ++j) {
    float wR = WihT[(64+j)*SW + lane], wZ = WihT[(64+j)*SW + 64 + lane], wN = WihT[(64+j)*SW + 128 + lane];
    #pragma unroll
    for (int rr = 0; rr < 4; ++rr) {
      float m = __shfl(v_d[rr], j);
      accR[rr] = fmaf(wR, m, accR[rr]); accZ[rr] = fmaf(wZ, m, accZ[rr]); accN[rr] = fmaf(wN, m, accN[rr]);
    }
  }
  // msg[128] = delta_t, msg[129] = edge_feat
  {
    float wR = WihT[128*SW + lane], wZ = WihT[128*SW + 64 + lane], wN = WihT[128*SW + 128 + lane];
    #pragma unroll
    for (int rr = 0; rr < 4; ++rr) {
      accR[rr] = fmaf(wR, dt[rr], accR[rr]); accZ[rr] = fmaf(wZ, dt[rr], accZ[rr]); accN[rr] = fmaf(wN, dt[rr], accN[rr]);
    }
    float eR = WihT[129*SW + lane], eZ = WihT[129*SW + 64 + lane], eN = WihT[129*SW + 128 + lane];
    #pragma unroll
    for (int rr = 0; rr < 4; ++rr) {
      accR[rr] = fmaf(eR, ef[rr], accR[rr]); accZ[rr] = fmaf(eZ, ef[rr], accZ[rr]); accN[rr] = fmaf(eN, ef[rr], accN[rr]);
    }
  }
  // gh: h @ W_hh^T  (r,z fold into acc; n kept separate)
  for (int j = 0; j < 64; ++j) {
    float wR = WhhT[j*SW + lane], wZ = WhhT[j*SW + 64 + lane], wN = WhhT[j*SW + 128 + lane];
    #pragma unroll
    for (int rr = 0; rr < 4; ++rr) {
      float m = __shfl(h_d[rr], j);
      accR[rr] = fmaf(wR, m, accR[rr]); accZ[rr] = fmaf(wZ, m, accZ[rr]); hN[rr] = fmaf(wN, m, hN[rr]);
    }
  }

  #pragma unroll
  for (int rr = 0; rr < 4; ++rr) {
    float r = 1.0f / (1.0f + expf(-accR[rr]));
    float z = 1.0f / (1.0f + expf(-accZ[rr]));
    float n = tanhf(accN[rr] + r * hN[rr]);
    float hn = (1.0f - z) * n + z * h_d[rr];
    h_new_out[bb[rr]*64 + lane] = hn;
  }
}

// ---------------- kernel 4: 2-token 4-head attention + out-proj -> z_u ----------------
__global__ __launch_bounds__(256) void attn_kernel(
    const int* __restrict__ u, const int* __restrict__ v,
    const float* __restrict__ edge_feat,
    const float* __restrict__ user_emb, const float* __restrict__ item_emb,
    const float* __restrict__ in_w, const float* __restrict__ in_b,
    const float* __restrict__ out_w, const float* __restrict__ out_b,
    float* __restrict__ z_out)
{
  __shared__ float inT[64*SW];     // [j][k], j<64, k<192
  __shared__ float outT[64*65];    // [j][k], j,k<64
  __shared__ float binp[192];
  __shared__ float bout[64];
  const int tid = threadIdx.x;

  for (int idx = tid; idx < 192*64; idx += 256) {
    int k = idx >> 6, j = idx & 63;
    inT[j*SW + k] = in_w[idx];
  }
  for (int idx = tid; idx < 64*64; idx += 256) {
    int k = idx >> 6, j = idx & 63;
    outT[j*65 + k] = out_w[idx];
  }
  if (tid < 192) binp[tid] = in_b[tid];
  if (tid < 64)  bout[tid] = out_b[tid];
  __syncthreads();

  const int lane = tid & 63, wid = tid >> 6;
  const int rowbase = blockIdx.x * 8 + wid * 2;

  float u_d[2], x1_d[2];
  int bb[2];
  #pragma unroll
  for (int rr = 0; rr < 2; ++rr) {
    int b = rowbase + rr; bb[rr] = b;
    int uu = u[b], vv = v[b];
    float ef = edge_feat[b];
    u_d[rr]  = user_emb[uu*64 + lane];
    x1_d[rr] = item_emb[vv*64 + lane] + ef;
  }

  float bq = binp[lane], bk = binp[64+lane], bv = binp[128+lane];
  float q0[2], k0[2], v0[2], k1[2], v1[2];
  #pragma unroll
  for (int rr = 0; rr < 2; ++rr) { q0[rr]=bq; k0[rr]=bk; v0[rr]=bv; k1[rr]=bk; v1[rr]=bv; }

  for (int j = 0; j < 64; ++j) {
    float wq = inT[j*SW + lane], wk = inT[j*SW + 64 + lane], wv = inT[j*SW + 128 + lane];
    #pragma unroll
    for (int rr = 0; rr < 2; ++rr) {
      float x0 = __shfl(u_d[rr], j);
      float x1 = __shfl(x1_d[rr], j);
      q0[rr] = fmaf(wq, x0, q0[rr]);
      k0[rr] = fmaf(wk, x0, k0[rr]);
      v0[rr] = fmaf(wv, x0, v0[rr]);
      k1[rr] = fmaf(wk, x1, k1[rr]);
      v1[rr] = fmaf(wv, x1, v1[rr]);
    }
  }

  #pragma unroll
  for (int rr = 0; rr < 2; ++rr) {
    // per-head (16-lane group) dot products
    float p0 = q0[rr]*k0[rr], p1 = q0[rr]*k1[rr];
    #pragma unroll
    for (int off = 1; off < 16; off <<= 1) { p0 += __shfl_xor(p0, off); p1 += __shfl_xor(p1, off); }
    float s0 = p0 * 0.25f, s1 = p1 * 0.25f;
    float m  = fmaxf(s0, s1);
    float e0 = expf(s0 - m), e1 = expf(s1 - m);
    float inv = 1.0f / (e0 + e1);
    float o_d = (e0 * v0[rr] + e1 * v1[rr]) * inv;
    // out projection: z[lane] = b + sum_j o[j] * W_out[lane][j]
    float zacc = bout[lane];
    for (int j = 0; j < 64; ++j)
      zacc = fmaf(outT[j*65 + lane], __shfl(o_d, j), zacc);
    z_out[bb[rr]*64 + lane] = zacc;
  }
}

// ---------------- launch ----------------
extern "C" void kernel_launch(void* const* d_in, const int* in_sizes, int n_in,
                              void* d_out, int out_size, void* d_ws, size_t ws_size,
                              hipStream_t stream)
{
  const int*   u        = (const int*)d_in[0];
  const int*   v        = (const int*)d_in[1];
  /* t = d_in[2] unused */
  const float* delta_t  = (const float*)d_in[3];
  const float* edge_f   = (const float*)d_in[4];
  const float* returns  = (const float*)d_in[5];
  const float* cov      = (const float*)d_in[6];
  const float* user_emb = (const float*)d_in[7];
  const float* item_emb = (const float*)d_in[8];
  const float* mem      = (const float*)d_in[9];
  const float* w_ih     = (const float*)d_in[10];
  const float* w_hh     = (const float*)d_in[11];
  const float* b_ih     = (const float*)d_in[12];
  const float* b_hh     = (const float*)d_in[13];
  const float* in_w     = (const float*)d_in[14];
  const float* in_b     = (const float*)d_in[15];
  const float* out_w    = (const float*)d_in[16];
  const float* out_b    = (const float*)d_in[17];

  float* out     = (float*)d_out;
  float* z_out   = out;                    // B*D
  float* h_out   = out + BB_*DD_;          // B*D
  float* pos_out = out + 2*BB_*DD_;        // B
  float* neg_out = out + 2*BB_*DD_ + BB_;  // B*3

  float* combined = (float*)d_ws;          // NI_ floats

  hipLaunchKernelGGL(matvec_combined_kernel, dim3(2500), dim3(256), 0, stream,
                     v, returns, cov, combined);
  hipLaunchKernelGGL(top5_items_kernel, dim3(1), dim3(1024), 0, stream,
                     combined, v, pos_out, neg_out);
  hipLaunchKernelGGL(gru_kernel, dim3(256), dim3(256), 0, stream,
                     u, v, delta_t, edge_f, user_emb, item_emb, mem,
                     w_ih, w_hh, b_ih, b_hh, h_out);
  hipLaunchKernelGGL(attn_kernel, dim3(512), dim3(256), 0, stream,
                     u, v, edge_f, user_emb, item_emb,
                     in_w, in_b, out_w, out_b, z_out);
}

// Round 5
// 152.759 us; speedup vs baseline: 1.0592x; 1.0329x over previous
//
#include <hip/hip_runtime.h>
#include <math.h>

#define BB_ 4096      // batch
#define DD_ 64        // emb dim
#define NI_ 10000     // items
#define SW 193        // padded LDS stride for transposed weights (193%32=1 -> conflict-free)
#define S1_BLOCKS 40  // top-5 stage-1 blocks (250 items each)

typedef unsigned long long u64;

// ---------------- threefry2x32 (JAX PRNG, key=42, partitionable path) ----------------
// bits[i] = xor(threefry2x32(key=(0,42), (0, i)));  uniform = float(bits>>9|0x3F800000)-1
__device__ inline unsigned rotl32(unsigned x, unsigned r){ return (x<<r)|(x>>(32u-r)); }

__device__ inline float jax_uniform_key42(int i){
  const unsigned k0 = 0u, k1 = 42u;
  const unsigned ks2 = 0x1BD11BDAu ^ k0 ^ k1;
  unsigned x0 = 0u, x1 = (unsigned)i;               // counter (hi, lo) = (0, i)
  unsigned ks[3] = {k0, k1, ks2};
  x0 += ks[0]; x1 += ks[1];
  const unsigned R0[4] = {13u,15u,26u,6u};
  const unsigned R1[4] = {17u,29u,16u,24u};
  #pragma unroll
  for (int it = 0; it < 5; ++it){
    const unsigned* R = (it & 1) ? R1 : R0;
    #pragma unroll
    for (int j = 0; j < 4; ++j){ x0 += x1; x1 = rotl32(x1, R[j]); x1 ^= x0; }
    x0 += ks[(it+1)%3];
    x1 += ks[(it+2)%3] + (unsigned)(it+1);
  }
  unsigned bits = x0 ^ x1;                          // partitionable 32-bit tail
  unsigned f = (bits >> 9) | 0x3F800000u;
  return __uint_as_float(f) - 1.0f;
}

// ---------------- kernel 0: histogram of v into ws (float counts) ----------------
__global__ __launch_bounds__(1024) void hist_kernel(
    const int* __restrict__ v, float* __restrict__ w_out)
{
  __shared__ float wl[NI_];
  const int tid = threadIdx.x;
  for (int i = tid; i < NI_; i += 1024) wl[i] = 0.0f;
  __syncthreads();
  for (int i = tid; i < BB_; i += 1024) atomicAdd(&wl[v[i]], 1.0f);
  __syncthreads();
  for (int i = tid; i < NI_; i += 1024) w_out[i] = wl[i];
}

// ---------------- kernel 1: wave-per-row weighted matvec (no atomics, no barriers) ----------------
// 2500 blocks x 256 threads; wave w of block b owns row b*4+w. Histogram is
// copied 40KB global->LDS (float4) once per block, then pure streaming.
__global__ __launch_bounds__(256) void matvec_combined_kernel(
    const float* __restrict__ w_in, const float* __restrict__ returns,
    const float* __restrict__ cov, float* __restrict__ combined)
{
  __shared__ __align__(16) float w[NI_];
  const int tid = threadIdx.x;
  {
    const float4* src = (const float4*)w_in;
    float4* dst = (float4*)w;
    for (int i = tid; i < NI_/4; i += 256) dst[i] = src[i];
  }
  __syncthreads();

  const int lane = tid & 63, wid = tid >> 6;
  const int row = blockIdx.x * 4 + wid;             // gridDim = 2500 -> rows 0..9999
  const float4* w4 = (const float4*)w;
  const float4* r4 = (const float4*)(cov + (size_t)row * NI_);

  float acc0 = 0.0f, acc1 = 0.0f;
  int k = lane;
  for (; k + 64 < NI_/4; k += 128) {
    float4 c0 = r4[k],     ww0 = w4[k];
    float4 c1 = r4[k+64],  ww1 = w4[k+64];
    acc0 += c0.x*ww0.x + c0.y*ww0.y + c0.z*ww0.z + c0.w*ww0.w;
    acc1 += c1.x*ww1.x + c1.y*ww1.y + c1.z*ww1.z + c1.w*ww1.w;
  }
  if (k < NI_/4) {
    float4 c0 = r4[k], ww0 = w4[k];
    acc0 += c0.x*ww0.x + c0.y*ww0.y + c0.z*ww0.z + c0.w*ww0.w;
  }
  float acc = acc0 + acc1;
  #pragma unroll
  for (int off = 32; off > 0; off >>= 1) acc += __shfl_xor(acc, off);

  if (lane == 0) {
    float cov_val = acc * (1.0f / (float)BB_);
    float mv = returns[row] - 0.5f * cov_val;       // GAMMA = 1
    float pref = jax_uniform_key42(row);
    combined[row] = 0.5f * mv + 0.5f * pref;        // LAM = 0.5
  }
}

// ---------------- top-5 helpers ----------------
__device__ inline u64 shfl_down_u64(u64 x, int off){
  unsigned lo = (unsigned)(x & 0xFFFFFFFFull), hi = (unsigned)(x >> 32);
  lo = __shfl_down(lo, off); hi = __shfl_down(hi, off);
  return ((u64)hi << 32) | (u64)lo;
}

__device__ inline u64 make_key(float val, int i){
  unsigned u = __float_as_uint(val);
  u ^= (u >> 31) ? 0xFFFFFFFFu : 0x80000000u;       // order-preserving float->uint
  return ((u64)u << 32) | (u64)(0xFFFFFFFFu - (unsigned)i); // tie: lower idx wins
}

// ---------------- kernel 2a: per-slice top-5 (register-resident, 1 item/thread) ----------------
__global__ __launch_bounds__(256) void top5_stage1(
    const float* __restrict__ combined, u64* __restrict__ keys_out)
{
  __shared__ u64 redL[4];
  __shared__ u64 sel;
  const int tid = threadIdx.x, lane = tid & 63, wid = tid >> 6;
  const int i = blockIdx.x * 250 + tid;

  u64 key = 0ull;
  if (tid < 250 && i < NI_) key = make_key(combined[i], i);

  for (int r = 0; r < 5; ++r) {
    u64 best = key;
    #pragma unroll
    for (int off = 32; off > 0; off >>= 1) {
      u64 o = shfl_down_u64(best, off);
      if (o > best) best = o;
    }
    if (lane == 0) redL[wid] = best;
    __syncthreads();                                 // barrier 1
    if (tid == 0) {
      u64 b = redL[0];
      for (int wv = 1; wv < 4; ++wv) if (redL[wv] > b) b = redL[wv];
      sel = b;
      keys_out[blockIdx.x * 5 + r] = b;
    }
    __syncthreads();                                 // barrier 2
    if (key == sel) key = 0ull;                      // invalidate chosen
  }
}

// ---------------- kernel 2b: global top-5 from 200 keys + pos/neg emit ----------------
__global__ __launch_bounds__(256) void top5_stage2(
    const u64* __restrict__ keys_in, const int* __restrict__ v,
    float* __restrict__ pos_out, float* __restrict__ neg_out)
{
  __shared__ u64 redL[4];
  __shared__ u64 sel;
  __shared__ int chosen[5];
  const int tid = threadIdx.x, lane = tid & 63, wid = tid >> 6;

  u64 key = (tid < 5 * S1_BLOCKS) ? keys_in[tid] : 0ull;

  for (int r = 0; r < 5; ++r) {
    u64 best = key;
    #pragma unroll
    for (int off = 32; off > 0; off >>= 1) {
      u64 o = shfl_down_u64(best, off);
      if (o > best) best = o;
    }
    if (lane == 0) redL[wid] = best;
    __syncthreads();
    if (tid == 0) {
      u64 b = redL[0];
      for (int wv = 1; wv < 4; ++wv) if (redL[wv] > b) b = redL[wv];
      sel = b;
      chosen[r] = (int)(0xFFFFFFFFu - (unsigned)(b & 0xFFFFFFFFull));
    }
    __syncthreads();
    if (key == sel) key = 0ull;
  }

  for (int b = tid; b < BB_; b += 256) {
    int vb = v[b];
    int f[4]; int n = 0;
    #pragma unroll
    for (int c = 0; c < 5; ++c) { if (n < 4 && chosen[c] != vb) f[n++] = chosen[c]; }
    pos_out[b]       = (float)f[0];
    neg_out[b*3 + 0] = (float)f[1];
    neg_out[b*3 + 1] = (float)f[2];
    neg_out[b*3 + 2] = (float)f[3];
  }
}

// ---------------- kernel 3: GRU memory update -> h_new ----------------
__global__ __launch_bounds__(256) void gru_kernel(
    const int* __restrict__ u, const int* __restrict__ v,
    const float* __restrict__ delta_t, const float* __restrict__ edge_feat,
    const float* __restrict__ user_emb, const float* __restrict__ item_emb,
    const float* __restrict__ mem,
    const float* __restrict__ w_ih, const float* __restrict__ w_hh,
    const float* __restrict__ b_ih, const float* __restrict__ b_hh,
    float* __restrict__ h_new_out)
{
  __shared__ float WihT[130*SW];   // [j][k], k<192
  __shared__ float WhhT[64*SW];    // [j][k], k<192
  __shared__ float bih[192], bhh[192];
  const int tid = threadIdx.x;

  for (int idx = tid; idx < 192*130; idx += 256) {
    int k = idx / 130, j = idx - k*130;
    WihT[j*SW + k] = w_ih[idx];
  }
  for (int idx = tid; idx < 192*64; idx += 256) {
    int k = idx >> 6, j = idx & 63;
    WhhT[j*SW + k] = w_hh[idx];
  }
  if (tid < 192) { bih[tid] = b_ih[tid]; bhh[tid] = b_hh[tid]; }
  __syncthreads();

  const int lane = tid & 63, wid = tid >> 6;
  const int rowbase = blockIdx.x * 16 + wid * 4;

  float u_d[4], v_d[4], h_d[4], dt[4], ef[4];
  int bb[4];
  #pragma unroll
  for (int rr = 0; rr < 4; ++rr) {
    int b = rowbase + rr; bb[rr] = b;
    int uu = u[b], vv = v[b];
    u_d[rr] = user_emb[uu*64 + lane];
    v_d[rr] = item_emb[vv*64 + lane];
    h_d[rr] = mem[uu*64 + lane];
    dt[rr]  = delta_t[b];
    ef[rr]  = edge_feat[b];
  }

  float biR = bih[lane], biZ = bih[64+lane], biN = bih[128+lane];
  float bhR = bhh[lane], bhZ = bhh[64+lane], bhN = bhh[128+lane];
  float accR[4], accZ[4], accN[4], hN[4];
  #pragma unroll
  for (int rr = 0; rr < 4; ++rr) { accR[rr]=biR+bhR; accZ[rr]=biZ+bhZ; accN[rr]=biN; hN[rr]=bhN; }

  // msg[0:64] = u_emb
  for (int j = 0; j < 64; ++j) {
    float wR = WihT[j*SW + lane], wZ = WihT[j*SW + 64 + lane], wN = WihT[j*SW + 128 + lane];
    #pragma unroll
    for (int rr = 0; rr < 4; ++rr) {
      float m = __shfl(u_d[rr], j);
      accR[rr] = fmaf(wR, m, accR[rr]); accZ[rr] = fmaf(wZ, m, accZ[rr]); accN[rr] = fmaf(wN, m, accN[rr]);
    }
  }
  // msg[64:128] = v_emb
  for (int j = 0; j < 64; ++j) {
    float wR = WihT[(64+j)*SW + lane], wZ = WihT[(64+j)*SW + 64 + lane], wN = WihT[(64+j)*SW + 128 + lane];
    #pragma unroll
    for (int rr = 0; rr < 4; ++rr) {
      float m = __shfl(v_d[rr], j);
      accR[rr] = fmaf(wR, m, accR[rr]); accZ[rr] = fmaf(wZ, m, accZ[rr]); accN[rr] = fmaf(wN, m, accN[rr]);
    }
  }
  // msg[128] = delta_t, msg[129] = edge_feat
  {
    float wR = WihT[128*SW + lane], wZ = WihT[128*SW + 64 + lane], wN = WihT[128*SW + 128 + lane];
    #pragma unroll
    for (int rr = 0; rr < 4; ++rr) {
      accR[rr] = fmaf(wR, dt[rr], accR[rr]); accZ[rr] = fmaf(wZ, dt[rr], accZ[rr]); accN[rr] = fmaf(wN, dt[rr], accN[rr]);
    }
    float eR = WihT[129*SW + lane], eZ = WihT[129*SW + 64 + lane], eN = WihT[129*SW + 128 + lane];
    #pragma unroll
    for (int rr = 0; rr < 4; ++rr) {
      accR[rr] = fmaf(eR, ef[rr], accR[rr]); accZ[rr] = fmaf(eZ, ef[rr], accZ[rr]); accN[rr] = fmaf(eN, ef[rr], accN[rr]);
    }
  }
  // gh: h @ W_hh^T  (r,z fold into acc; n kept separate)
  for (int j = 0; j < 64; ++j) {
    float wR = WhhT[j*SW + lane], wZ = WhhT[j*SW + 64 + lane], wN = WhhT[j*SW + 128 + lane];
    #pragma unroll
    for (int rr = 0; rr < 4; ++rr) {
      float m = __shfl(h_d[rr], j);
      accR[rr] = fmaf(wR, m, accR[rr]); accZ[rr] = fmaf(wZ, m, accZ[rr]); hN[rr] = fmaf(wN, m, hN[rr]);
    }
  }

  #pragma unroll
  for (int rr = 0; rr < 4; ++rr) {
    float r = 1.0f / (1.0f + expf(-accR[rr]));
    float z = 1.0f / (1.0f + expf(-accZ[rr]));
    float n = tanhf(accN[rr] + r * hN[rr]);
    float hn = (1.0f - z) * n + z * h_d[rr];
    h_new_out[bb[rr]*64 + lane] = hn;
  }
}

// ---------------- kernel 4: 2-token 4-head attention + out-proj -> z_u ----------------
__global__ __launch_bounds__(256) void attn_kernel(
    const int* __restrict__ u, const int* __restrict__ v,
    const float* __restrict__ edge_feat,
    const float* __restrict__ user_emb, const float* __restrict__ item_emb,
    const float* __restrict__ in_w, const float* __restrict__ in_b,
    const float* __restrict__ out_w, const float* __restrict__ out_b,
    float* __restrict__ z_out)
{
  __shared__ float inT[64*SW];     // [j][k], j<64, k<192
  __shared__ float outT[64*65];    // [j][k], j,k<64
  __shared__ float binp[192];
  __shared__ float bout[64];
  const int tid = threadIdx.x;

  for (int idx = tid; idx < 192*64; idx += 256) {
    int k = idx >> 6, j = idx & 63;
    inT[j*SW + k] = in_w[idx];
  }
  for (int idx = tid; idx < 64*64; idx += 256) {
    int k = idx >> 6, j = idx & 63;
    outT[j*65 + k] = out_w[idx];
  }
  if (tid < 192) binp[tid] = in_b[tid];
  if (tid < 64)  bout[tid] = out_b[tid];
  __syncthreads();

  const int lane = tid & 63, wid = tid >> 6;
  const int rowbase = blockIdx.x * 8 + wid * 2;

  float u_d[2], x1_d[2];
  int bb[2];
  #pragma unroll
  for (int rr = 0; rr < 2; ++rr) {
    int b = rowbase + rr; bb[rr] = b;
    int uu = u[b], vv = v[b];
    float ef = edge_feat[b];
    u_d[rr]  = user_emb[uu*64 + lane];
    x1_d[rr] = item_emb[vv*64 + lane] + ef;
  }

  float bq = binp[lane], bk = binp[64+lane], bv = binp[128+lane];
  float q0[2], k0[2], v0[2], k1[2], v1[2];
  #pragma unroll
  for (int rr = 0; rr < 2; ++rr) { q0[rr]=bq; k0[rr]=bk; v0[rr]=bv; k1[rr]=bk; v1[rr]=bv; }

  for (int j = 0; j < 64; ++j) {
    float wq = inT[j*SW + lane], wk = inT[j*SW + 64 + lane], wv = inT[j*SW + 128 + lane];
    #pragma unroll
    for (int rr = 0; rr < 2; ++rr) {
      float x0 = __shfl(u_d[rr], j);
      float x1 = __shfl(x1_d[rr], j);
      q0[rr] = fmaf(wq, x0, q0[rr]);
      k0[rr] = fmaf(wk, x0, k0[rr]);
      v0[rr] = fmaf(wv, x0, v0[rr]);
      k1[rr] = fmaf(wk, x1, k1[rr]);
      v1[rr] = fmaf(wv, x1, v1[rr]);
    }
  }

  #pragma unroll
  for (int rr = 0; rr < 2; ++rr) {
    // per-head (16-lane group) dot products
    float p0 = q0[rr]*k0[rr], p1 = q0[rr]*k1[rr];
    #pragma unroll
    for (int off = 1; off < 16; off <<= 1) { p0 += __shfl_xor(p0, off); p1 += __shfl_xor(p1, off); }
    float s0 = p0 * 0.25f, s1 = p1 * 0.25f;
    float m  = fmaxf(s0, s1);
    float e0 = expf(s0 - m), e1 = expf(s1 - m);
    float inv = 1.0f / (e0 + e1);
    float o_d = (e0 * v0[rr] + e1 * v1[rr]) * inv;
    // out projection: z[lane] = b + sum_j o[j] * W_out[lane][j]
    float zacc = bout[lane];
    for (int j = 0; j < 64; ++j)
      zacc = fmaf(outT[j*65 + lane], __shfl(o_d, j), zacc);
    z_out[bb[rr]*64 + lane] = zacc;
  }
}

// ---------------- launch ----------------
extern "C" void kernel_launch(void* const* d_in, const int* in_sizes, int n_in,
                              void* d_out, int out_size, void* d_ws, size_t ws_size,
                              hipStream_t stream)
{
  const int*   u        = (const int*)d_in[0];
  const int*   v        = (const int*)d_in[1];
  /* t = d_in[2] unused */
  const float* delta_t  = (const float*)d_in[3];
  const float* edge_f   = (const float*)d_in[4];
  const float* returns  = (const float*)d_in[5];
  const float* cov      = (const float*)d_in[6];
  const float* user_emb = (const float*)d_in[7];
  const float* item_emb = (const float*)d_in[8];
  const float* mem      = (const float*)d_in[9];
  const float* w_ih     = (const float*)d_in[10];
  const float* w_hh     = (const float*)d_in[11];
  const float* b_ih     = (const float*)d_in[12];
  const float* b_hh     = (const float*)d_in[13];
  const float* in_w     = (const float*)d_in[14];
  const float* in_b     = (const float*)d_in[15];
  const float* out_w    = (const float*)d_in[16];
  const float* out_b    = (const float*)d_in[17];

  float* out     = (float*)d_out;
  float* z_out   = out;                    // B*D
  float* h_out   = out + BB_*DD_;          // B*D
  float* pos_out = out + 2*BB_*DD_;        // B
  float* neg_out = out + 2*BB_*DD_ + BB_;  // B*3

  float* ws        = (float*)d_ws;
  float* w_hist    = ws;                   // NI_ floats (histogram, 16B-aligned)
  float* combined  = ws + 10240;           // NI_ floats
  u64*   keys      = (u64*)(ws + 20480);   // S1_BLOCKS*5 u64 (8B-aligned offset)

  hipLaunchKernelGGL(hist_kernel, dim3(1), dim3(1024), 0, stream, v, w_hist);
  hipLaunchKernelGGL(matvec_combined_kernel, dim3(2500), dim3(256), 0, stream,
                     w_hist, returns, cov, combined);
  hipLaunchKernelGGL(top5_stage1, dim3(S1_BLOCKS), dim3(256), 0, stream,
                     combined, keys);
  hipLaunchKernelGGL(top5_stage2, dim3(1), dim3(256), 0, stream,
                     keys, v, pos_out, neg_out);
  hipLaunchKernelGGL(gru_kernel, dim3(256), dim3(256), 0, stream,
                     u, v, delta_t, edge_f, user_emb, item_emb, mem,
                     w_ih, w_hh, b_ih, b_hh, h_out);
  hipLaunchKernelGGL(attn_kernel, dim3(512), dim3(256), 0, stream,
                     u, v, edge_f, user_emb, item_emb,
                     in_w, in_b, out_w, out_b, z_out);
}